// Round 1
// baseline (729.285 us; speedup 1.0000x reference)
//
#include <hip/hip_runtime.h>

#define NTG 128
#define SEQL 8192
#define NSTEPS (SEQL-1)      // 8191
#define GCH 512              // chunks
#define LCH 16               // steps per chunk (GCH*LCH = 8192 >= NSTEPS)
#define MATF (NTG*NTG)       // 16384 floats per matrix

__device__ __forceinline__ float wave_max(float v){
#pragma unroll
  for (int m = 32; m >= 1; m >>= 1) v = fmaxf(v, __shfl_xor(v, m));
  return v;
}
__device__ __forceinline__ float wave_sum(float v){
#pragma unroll
  for (int m = 32; m >= 1; m >>= 1) v += __shfl_xor(v, m);
  return v;
}

// ---------------- kernel 0: E = exp(T) ----------------
__global__ void k_expT(const float* __restrict__ T, float* __restrict__ E){
  int i = blockIdx.x*256 + threadIdx.x;
  if (i < MATF) E[i] = expf(T[i]);
}

// ---------------- kernel 1: per-chunk scaled transfer matrices ----------------
// Chunk g covers steps s0..s0+nst-1 (emit row x[1+s]).
// Maintains M (scaled exp of log-semiring product) transposed in LDS:
//   Mt[k*128+i] = M[i][k],  max entry renormalized to 1 each step,
//   log-scale accumulated in double cacc.
__global__ __launch_bounds__(256, 2)
void k_chunks(const int* __restrict__ x, const float* __restrict__ emit,
              const float* __restrict__ E, float* __restrict__ P,
              double* __restrict__ scale)
{
  __shared__ float Mt[NTG*NTG];
  __shared__ float red_m[4];
  __shared__ float red_g[4];

  const int t   = threadIdx.x;
  const int ti  = t & 15, tj = t >> 4;       // ti fast within wave -> contiguous LDS reads
  const int wv  = t >> 6, lane = t & 63;
  const int i0  = ti*8, j0 = tj*8;
  const int g   = blockIdx.x;
  const int s0  = g*LCH;
  const int nst = min(LCH, NSTEPS - s0);     // 16, last chunk 15

  double cacc;
  float acc[8][8];

  // ---- leaf: M = E .* exp(emit_{s0} - m) (column scaling), c = m ----
  {
    const int tok = x[1+s0];
    const float* er = emit + (size_t)tok*NTG + j0;
    float e8[8];
    { float4 u = *(const float4*)er;     e8[0]=u.x; e8[1]=u.y; e8[2]=u.z; e8[3]=u.w; }
    { float4 u = *(const float4*)(er+4); e8[4]=u.x; e8[5]=u.y; e8[6]=u.z; e8[7]=u.w; }
    float pm = e8[0];
#pragma unroll
    for (int c=1;c<8;c++) pm = fmaxf(pm, e8[c]);
    pm = wave_max(pm);
    if (lane==0) red_m[wv] = pm;
    __syncthreads();
    const float m = fmaxf(fmaxf(red_m[0],red_m[1]), fmaxf(red_m[2],red_m[3]));
    float eh[8];
#pragma unroll
    for (int c=0;c<8;c++) eh[c] = expf(e8[c]-m);
    float v[8][8];
#pragma unroll
    for (int r=0;r<8;r++){
      const float* Ep = E + (size_t)(i0+r)*NTG + j0;
      float4 u0 = *(const float4*)Ep; float4 u1 = *(const float4*)(Ep+4);
      v[r][0]=u0.x*eh[0]; v[r][1]=u0.y*eh[1]; v[r][2]=u0.z*eh[2]; v[r][3]=u0.w*eh[3];
      v[r][4]=u1.x*eh[4]; v[r][5]=u1.y*eh[5]; v[r][6]=u1.z*eh[6]; v[r][7]=u1.w*eh[7];
    }
#pragma unroll
    for (int c=0;c<8;c++){
      *(float4*)&Mt[(j0+c)*NTG + i0]   = make_float4(v[0][c],v[1][c],v[2][c],v[3][c]);
      *(float4*)&Mt[(j0+c)*NTG + i0+4] = make_float4(v[4][c],v[5][c],v[6][c],v[7][c]);
    }
    cacc = (double)m;
    __syncthreads();
  }

  // ---- remaining steps: C = (M*E) .* exp(emit_t - m_t), renorm by max ----
  for (int s=1; s<nst; ++s){
    const int tok = x[1+s0+s];
    const float* er = emit + (size_t)tok*NTG + j0;
    float e8[8];
    { float4 u = *(const float4*)er;     e8[0]=u.x; e8[1]=u.y; e8[2]=u.z; e8[3]=u.w; }
    { float4 u = *(const float4*)(er+4); e8[4]=u.x; e8[5]=u.y; e8[6]=u.z; e8[7]=u.w; }
    float pm = e8[0];
#pragma unroll
    for (int c=1;c<8;c++) pm = fmaxf(pm, e8[c]);
    pm = wave_max(pm);
    if (lane==0) red_m[wv] = pm;
    __syncthreads();                                    // bar1
    const float m = fmaxf(fmaxf(red_m[0],red_m[1]), fmaxf(red_m[2],red_m[3]));
    float eh[8];
#pragma unroll
    for (int c=0;c<8;c++) eh[c] = expf(e8[c]-m);

#pragma unroll
    for (int r=0;r<8;r++)
#pragma unroll
      for (int c=0;c<8;c++) acc[r][c] = 0.f;

    const float* Bp = E + j0;
    for (int k=0;k<NTG;k++){
      float a[8], b[8];
      { float4 u = *(const float4*)&Mt[k*NTG+i0];   a[0]=u.x;a[1]=u.y;a[2]=u.z;a[3]=u.w; }
      { float4 u = *(const float4*)&Mt[k*NTG+i0+4]; a[4]=u.x;a[5]=u.y;a[6]=u.z;a[7]=u.w; }
      { float4 u = *(const float4*)&Bp[(size_t)k*NTG];   b[0]=u.x;b[1]=u.y;b[2]=u.z;b[3]=u.w; }
      { float4 u = *(const float4*)&Bp[(size_t)k*NTG+4]; b[4]=u.x;b[5]=u.y;b[6]=u.z;b[7]=u.w; }
#pragma unroll
      for (int r=0;r<8;r++)
#pragma unroll
        for (int c=0;c<8;c++) acc[r][c] = fmaf(a[r], b[c], acc[r][c]);
    }

    float gm = -1.f;
#pragma unroll
    for (int r=0;r<8;r++)
#pragma unroll
      for (int c=0;c<8;c++){ acc[r][c] *= eh[c]; gm = fmaxf(gm, acc[r][c]); }
    gm = wave_max(gm);
    if (lane==0) red_g[wv] = gm;
    __syncthreads();                                    // bar2 (all Mt reads done)
    const float gmax = fmaxf(fmaxf(red_g[0],red_g[1]), fmaxf(red_g[2],red_g[3]));
    const float inv  = 1.0f/gmax;
    cacc += (double)m + (double)logf(gmax);
#pragma unroll
    for (int r=0;r<8;r++)
#pragma unroll
      for (int c=0;c<8;c++) acc[r][c] *= inv;
#pragma unroll
    for (int c=0;c<8;c++){
      *(float4*)&Mt[(j0+c)*NTG + i0]   = make_float4(acc[0][c],acc[1][c],acc[2][c],acc[3][c]);
      *(float4*)&Mt[(j0+c)*NTG + i0+4] = make_float4(acc[4][c],acc[5][c],acc[6][c],acc[7][c]);
    }
    __syncthreads();                                    // bar3 (Mt writes visible)
  }

  // store row-major P[g] from regs (acc holds the final normalized matrix)
  float* Pg = P + (size_t)g*MATF;
#pragma unroll
  for (int r=0;r<8;r++){
    *(float4*)&Pg[(size_t)(i0+r)*NTG + j0]   = make_float4(acc[r][0],acc[r][1],acc[r][2],acc[r][3]);
    *(float4*)&Pg[(size_t)(i0+r)*NTG + j0+4] = make_float4(acc[r][4],acc[r][5],acc[r][6],acc[r][7]);
  }
  if (t==0) scale[g] = cacc;
}

// ---------------- kernel 2: pairwise tree combine ----------------
__global__ __launch_bounds__(256, 2)
void k_comb(const float* __restrict__ Pin, const double* __restrict__ Sin,
            float* __restrict__ Pout, double* __restrict__ Sout)
{
  __shared__ float At[NTG*NTG];
  __shared__ float red_g[4];
  const int t  = threadIdx.x;
  const int ti = t & 15, tj = t >> 4;
  const int wv = t >> 6, lane = t & 63;
  const int i0 = ti*8, j0 = tj*8;
  const int p  = blockIdx.x;
  const float* A = Pin + (size_t)(2*p)*MATF;
  const float* B = Pin + (size_t)(2*p+1)*MATF;

  float v[8][8];
#pragma unroll
  for (int r=0;r<8;r++){
    const float* Ap = A + (size_t)(i0+r)*NTG + j0;
    float4 u0 = *(const float4*)Ap; float4 u1 = *(const float4*)(Ap+4);
    v[r][0]=u0.x; v[r][1]=u0.y; v[r][2]=u0.z; v[r][3]=u0.w;
    v[r][4]=u1.x; v[r][5]=u1.y; v[r][6]=u1.z; v[r][7]=u1.w;
  }
#pragma unroll
  for (int c=0;c<8;c++){
    *(float4*)&At[(j0+c)*NTG + i0]   = make_float4(v[0][c],v[1][c],v[2][c],v[3][c]);
    *(float4*)&At[(j0+c)*NTG + i0+4] = make_float4(v[4][c],v[5][c],v[6][c],v[7][c]);
  }
  __syncthreads();

  float acc[8][8];
#pragma unroll
  for (int r=0;r<8;r++)
#pragma unroll
    for (int c=0;c<8;c++) acc[r][c] = 0.f;

  const float* Bp = B + j0;
  for (int k=0;k<NTG;k++){
    float a[8], b[8];
    { float4 u = *(const float4*)&At[k*NTG+i0];   a[0]=u.x;a[1]=u.y;a[2]=u.z;a[3]=u.w; }
    { float4 u = *(const float4*)&At[k*NTG+i0+4]; a[4]=u.x;a[5]=u.y;a[6]=u.z;a[7]=u.w; }
    { float4 u = *(const float4*)&Bp[(size_t)k*NTG];   b[0]=u.x;b[1]=u.y;b[2]=u.z;b[3]=u.w; }
    { float4 u = *(const float4*)&Bp[(size_t)k*NTG+4]; b[4]=u.x;b[5]=u.y;b[6]=u.z;b[7]=u.w; }
#pragma unroll
    for (int r=0;r<8;r++)
#pragma unroll
      for (int c=0;c<8;c++) acc[r][c] = fmaf(a[r], b[c], acc[r][c]);
  }

  float gm = -1.f;
#pragma unroll
  for (int r=0;r<8;r++)
#pragma unroll
    for (int c=0;c<8;c++) gm = fmaxf(gm, acc[r][c]);
  gm = wave_max(gm);
  if (lane==0) red_g[wv] = gm;
  __syncthreads();
  const float gmax = fmaxf(fmaxf(red_g[0],red_g[1]), fmaxf(red_g[2],red_g[3]));
  const float inv  = 1.0f/gmax;

  float* Cp = Pout + (size_t)p*MATF;
#pragma unroll
  for (int r=0;r<8;r++){
#pragma unroll
    for (int c=0;c<8;c++) acc[r][c] *= inv;
    *(float4*)&Cp[(size_t)(i0+r)*NTG + j0]   = make_float4(acc[r][0],acc[r][1],acc[r][2],acc[r][3]);
    *(float4*)&Cp[(size_t)(i0+r)*NTG + j0+4] = make_float4(acc[r][4],acc[r][5],acc[r][6],acc[r][7]);
  }
  if (t==0) Sout[p] = Sin[2*p] + Sin[2*p+1] + (double)logf(gmax);
}

// ---------------- kernel 3: finalize z ----------------
__global__ void k_final(const float* __restrict__ Pf, const double* __restrict__ Sf,
                        const float* __restrict__ T, float* __restrict__ out)
{
  __shared__ float rmax[2], rsum[2];
  const int t = threadIdx.x;          // 128 threads
  const int wv = t>>6, lane = t&63;
  float val = logf(Pf[t]) + T[t*NTG + 1];   // row START=0 of product; END tag = 1
  float m = wave_max(val);
  if (lane==0) rmax[wv] = m;
  __syncthreads();
  m = fmaxf(rmax[0], rmax[1]);
  float e = expf(val - m);
  float s = wave_sum(e);
  if (lane==0) rsum[wv] = s;
  __syncthreads();
  if (t==0){
    double z = (double)m + log((double)(rsum[0]+rsum[1])) + Sf[0];
    out[0] = (float)z;
  }
}

extern "C" void kernel_launch(void* const* d_in, const int* in_sizes, int n_in,
                              void* d_out, int out_size, void* d_ws, size_t ws_size,
                              hipStream_t stream)
{
  const int*   x    = (const int*)d_in[0];
  const float* emit = (const float*)d_in[1];
  const float* T    = (const float*)d_in[2];
  float* out = (float*)d_out;

  // ws layout (floats): E[16384] | bufA[512*16384] | bufB[256*16384] | scA[512 dbl] | scB[256 dbl]
  float*  E    = (float*)d_ws;
  float*  bufA = E + MATF;
  float*  bufB = bufA + (size_t)GCH*MATF;
  double* scA  = (double*)(bufB + (size_t)(GCH/2)*MATF);
  double* scB  = scA + GCH;

  k_expT<<<MATF/256, 256, 0, stream>>>(T, E);
  k_chunks<<<GCH, 256, 0, stream>>>(x, emit, E, bufA, scA);

  const float*  pin = bufA; float*  pout = bufB;
  const double* si  = scA;  double* so   = scB;
  for (int n = GCH/2; n >= 1; n >>= 1){
    k_comb<<<n, 256, 0, stream>>>(pin, si, pout, so);
    const float* tp = pin; pin = pout; pout = (float*)tp;
    const double* ts = si; si = so; so = (double*)ts;
  }
  k_final<<<1, 128, 0, stream>>>(pin, si, T, out);
}

// Round 3
// 704.274 us; speedup vs baseline: 1.0355x; 1.0355x over previous
//
#include <hip/hip_runtime.h>

#define NTG 128
#define NSTEPS 8191          // SEQ_LEN-1
#define GCH 512              // chunks
#define LCH 16               // steps per chunk
#define MATH16 (NTG*NTG)     // elements per matrix

typedef _Float16 half4v  __attribute__((ext_vector_type(4)));
typedef float    float4v __attribute__((ext_vector_type(4)));

// swizzled index into a [128][128] f16 LDS tile (element units).
// XOR bits 3..6 with row bits 0..3 -> spreads stride-256B rows across banks,
// preserves 4-element (b64) and 2-element (b32) alignment.
__device__ __forceinline__ int su(int row, int col){
  return (row*NTG + col) ^ ((row & 15) << 3);
}

__device__ __forceinline__ float wave_max(float v){
#pragma unroll
  for (int m = 32; m >= 1; m >>= 1) v = fmaxf(v, __shfl_xor(v, m));
  return v;
}
__device__ __forceinline__ float wave_sum(float v){
#pragma unroll
  for (int m = 32; m >= 1; m >>= 1) v += __shfl_xor(v, m);
  return v;
}

// ---------------- kernel 1: per-chunk scaled transfer matrices (MFMA f16) ----------------
// State X = M_s row-major f16 (swizzled) in LDS, max-normalized; log-scale in double.
// Step: D = (E^T)(M_s^T) via mfma_16x16x16_f16; D[j][i]*eh[j], renorm, write X[i][j].
__global__ __launch_bounds__(256, 2)
void k_chunks(const int* __restrict__ x, const float* __restrict__ emit,
              const float* __restrict__ T, _Float16* __restrict__ P,
              double* __restrict__ scale)
{
  __shared__ _Float16 X[MATH16];   // 32 KB
  __shared__ float red_g[4];

  const int t    = threadIdx.x;
  const int lane = t & 63, wv = t >> 6;
  const int l15  = lane & 15, g4 = lane >> 4;   // lane>>4 in 0..3
  const int g    = blockIdx.x;
  const int s0   = g*LCH;
  const int nst  = min(LCH, NSTEPS - s0);       // 16 (last chunk 15)

  // --- preload A-fragments: A = E^T, A[j][k] = exp(T[k][j]); fixed for all steps.
  // frag(jt,ks): row j = 16*(2wv+jt)+l15, k = 16ks + 4*g4 + jj
  half4v aE[2][8];
#pragma unroll
  for (int jt=0; jt<2; ++jt){
    const int j = (wv*2 + jt)*16 + l15;
#pragma unroll
    for (int ks=0; ks<8; ++ks){
      half4v a;
#pragma unroll
      for (int jj=0; jj<4; ++jj){
        const int k = ks*16 + g4*4 + jj;
        a[jj] = (_Float16)__expf(T[k*NTG + j]);
      }
      aE[jt][ks] = a;
    }
  }

  // --- leaf: X = G_{s0}: X[i][j] = exp(T[i][j]) * eh0[j]
  double cacc;
  {
    const int tok = x[1+s0];
    const float* er = emit + (size_t)tok*NTG;
    float2 me2 = *(const float2*)(er + lane*2);
    const float m0 = wave_max(fmaxf(me2.x, me2.y));
    const float eh0a = __expf(me2.x - m0);      // cols 2*lane, 2*lane+1
    const float eh0b = __expf(me2.y - m0);
    const int j0 = (t & 63)*2;
    for (int it2=0; it2<32; ++it2){
      const int idx = it2*256 + t;
      const int i = idx >> 6;                   // row; j = j0 (2 cols per thread)
      float2 tv = *(const float2*)(T + (size_t)i*NTG + j0);
      union { unsigned int u; _Float16 h[2]; } pk;
      pk.h[0] = (_Float16)(__expf(tv.x)*eh0a);
      pk.h[1] = (_Float16)(__expf(tv.y)*eh0b);
      *(unsigned int*)&X[su(i, j0)] = pk.u;
    }
    cacc = (double)m0;
  }
  __syncthreads();

  float4v accv[2][8];
  for (int s=1; s<nst; ++s){
    const int tok = x[1+s0+s];
    const float* er = emit + (size_t)tok*NTG;
    float2 me2 = *(const float2*)(er + lane*2);
    const float m = wave_max(fmaxf(me2.x, me2.y));
    float eh[2][4];
#pragma unroll
    for (int jt=0; jt<2; ++jt)
#pragma unroll
      for (int r=0; r<4; ++r)
        eh[jt][r] = __expf(er[(wv*2+jt)*16 + g4*4 + r] - m);

#pragma unroll
    for (int jt=0; jt<2; ++jt)
#pragma unroll
      for (int it=0; it<8; ++it) accv[jt][it] = (float4v){0.f,0.f,0.f,0.f};

#pragma unroll 2
    for (int it=0; it<8; ++it){
      const int c = it*16 + l15;                // B col = i-index of M
      half4v bf[8];
#pragma unroll
      for (int ks=0; ks<8; ++ks)
        bf[ks] = *(half4v*)&X[su(c, ks*16 + g4*4)];   // B[k][c] = M[c][k]
#pragma unroll
      for (int jt=0; jt<2; ++jt)
#pragma unroll
        for (int ks=0; ks<8; ++ks)
          accv[jt][it] = __builtin_amdgcn_mfma_f32_16x16x16f16(aE[jt][ks], bf[ks], accv[jt][it], 0,0,0);
    }

    float gm = 0.f;
#pragma unroll
    for (int jt=0; jt<2; ++jt)
#pragma unroll
      for (int it=0; it<8; ++it)
#pragma unroll
        for (int r=0;r<4;r++){
          float v = accv[jt][it][r] * eh[jt][r];
          accv[jt][it][r] = v;
          gm = fmaxf(gm, v);
        }
    gm = wave_max(gm);
    if (lane==0) red_g[wv] = gm;
    __syncthreads();                            // barA: all B-frag reads done + red_g ready
    const float gmax = fmaxf(fmaxf(red_g[0],red_g[1]), fmaxf(red_g[2],red_g[3]));
    const float inv  = 1.0f/gmax;
    cacc += (double)m + (double)__logf(gmax);
#pragma unroll
    for (int jt=0; jt<2; ++jt)
#pragma unroll
      for (int it=0; it<8; ++it){
        const int i  = it*16 + l15;
        const int jb = (wv*2+jt)*16 + g4*4;
        half4v h;
#pragma unroll
        for (int r=0;r<4;r++) h[r] = (_Float16)(accv[jt][it][r]*inv);
        *(half4v*)&X[su(i, jb)] = h;            // X[i][jb..jb+3] contiguous
      }
    __syncthreads();                            // barB: X writes visible
  }

  // store row-major f16 P[g] (unswizzle via matching su reads)
  _Float16* Pg = P + (size_t)g*MATH16;
  for (int it2=0; it2<32; ++it2){
    const int idx = it2*256 + t;
    const int i = idx >> 6, j = (t & 63)*2;
    ((unsigned int*)Pg)[idx] = *(unsigned int*)&X[su(i, j)];
  }
  if (t==0) scale[g] = cacc;
}

// ---------------- kernel 2: fan-in-8 combine with per-multiply renorm (MFMA f16) ----------------
__global__ __launch_bounds__(256, 2)
void k_comb8(const _Float16* __restrict__ Pin, const double* __restrict__ Sin,
             _Float16* __restrict__ Pout, double* __restrict__ Sout)
{
  __shared__ _Float16 X[MATH16];
  __shared__ float red_g[4];
  const int t    = threadIdx.x;
  const int lane = t & 63, wv = t >> 6;
  const int l15  = lane & 15, g4 = lane >> 4;
  const int p    = blockIdx.x;
  const _Float16* A0 = Pin + (size_t)p*8*MATH16;

  // stage X = first matrix (row-major -> swizzled)
  for (int it2=0; it2<32; ++it2){
    const int idx = it2*256 + t;
    const int i = idx >> 6, j = (t & 63)*2;
    *(unsigned int*)&X[su(i, j)] = ((const unsigned int*)A0)[idx];
  }
  double slog = 0.0;
  __syncthreads();

  float4v accv[2][8];
  for (int mi=1; mi<8; ++mi){
    const _Float16* B = A0 + (size_t)mi*MATH16;
    // A-fragments = B^T from global: A[j][k] = B[k][j]
    half4v aB[2][8];
#pragma unroll
    for (int jt=0; jt<2; ++jt){
      const int j = (wv*2 + jt)*16 + l15;
#pragma unroll
      for (int ks=0; ks<8; ++ks){
        half4v a;
#pragma unroll
        for (int jj=0; jj<4; ++jj) a[jj] = B[(size_t)(ks*16 + g4*4 + jj)*NTG + j];
        aB[jt][ks] = a;
      }
    }

#pragma unroll
    for (int jt=0; jt<2; ++jt)
#pragma unroll
      for (int it=0; it<8; ++it) accv[jt][it] = (float4v){0.f,0.f,0.f,0.f};

#pragma unroll 2
    for (int it=0; it<8; ++it){
      const int c = it*16 + l15;
      half4v bf[8];
#pragma unroll
      for (int ks=0; ks<8; ++ks)
        bf[ks] = *(half4v*)&X[su(c, ks*16 + g4*4)];
#pragma unroll
      for (int jt=0; jt<2; ++jt)
#pragma unroll
        for (int ks=0; ks<8; ++ks)
          accv[jt][it] = __builtin_amdgcn_mfma_f32_16x16x16f16(aB[jt][ks], bf[ks], accv[jt][it], 0,0,0);
    }

    float gm = 0.f;
#pragma unroll
    for (int jt=0; jt<2; ++jt)
#pragma unroll
      for (int it=0; it<8; ++it)
#pragma unroll
        for (int r=0;r<4;r++) gm = fmaxf(gm, accv[jt][it][r]);
    gm = wave_max(gm);
    if (lane==0) red_g[wv] = gm;
    __syncthreads();
    const float gmax = fmaxf(fmaxf(red_g[0],red_g[1]), fmaxf(red_g[2],red_g[3]));
    const float inv  = 1.0f/gmax;
    slog += (double)__logf(gmax);
#pragma unroll
    for (int jt=0; jt<2; ++jt)
#pragma unroll
      for (int it=0; it<8; ++it){
        const int i  = it*16 + l15;
        const int jb = (wv*2+jt)*16 + g4*4;
        half4v h;
#pragma unroll
        for (int r=0;r<4;r++) h[r] = (_Float16)(accv[jt][it][r]*inv);
        *(half4v*)&X[su(i, jb)] = h;
      }
    __syncthreads();
  }

  _Float16* Po = Pout + (size_t)p*MATH16;
  for (int it2=0; it2<32; ++it2){
    const int idx = it2*256 + t;
    const int i = idx >> 6, j = (t & 63)*2;
    ((unsigned int*)Po)[idx] = *(unsigned int*)&X[su(i, j)];
  }
  if (t==0){
    double ssum = slog;
    for (int q=0;q<8;q++) ssum += Sin[p*8+q];
    Sout[p] = ssum;
  }
}

// ---------------- kernel 3: finalize z ----------------
__global__ void k_final(const _Float16* __restrict__ Pf, const double* __restrict__ Sf,
                        const float* __restrict__ T, float* __restrict__ out)
{
  __shared__ float rmax[2], rsum[2];
  const int t = threadIdx.x;          // 128 threads
  const int wv = t>>6, lane = t&63;
  float val = logf((float)Pf[t]) + T[t*NTG + 1];   // row START=0 of product; END tag = 1
  float mx = wave_max(val);
  if (lane==0) rmax[wv] = mx;
  __syncthreads();
  mx = fmaxf(rmax[0], rmax[1]);
  float e = expf(val - mx);
  float s = wave_sum(e);
  if (lane==0) rsum[wv] = s;
  __syncthreads();
  if (t==0){
    double z = (double)mx + log((double)(rsum[0]+rsum[1])) + Sf[0];
    out[0] = (float)z;
  }
}

extern "C" void kernel_launch(void* const* d_in, const int* in_sizes, int n_in,
                              void* d_out, int out_size, void* d_ws, size_t ws_size,
                              hipStream_t stream)
{
  const int*   x    = (const int*)d_in[0];
  const float* emit = (const float*)d_in[1];
  const float* T    = (const float*)d_in[2];
  float* out = (float*)d_out;

  // ws: f16 bufA[512 mats] | bufB[64] | bufC[8] | bufD[1] | doubles scA[512] scB[64] scC[8] scD[1]
  _Float16* bufA = (_Float16*)d_ws;
  _Float16* bufB = bufA + (size_t)512*MATH16;
  _Float16* bufC = bufB + (size_t)64*MATH16;
  _Float16* bufD = bufC + (size_t)8*MATH16;
  double* scA = (double*)(bufD + MATH16);
  double* scB = scA + 512;
  double* scC = scB + 64;
  double* scD = scC + 8;

  k_chunks<<<GCH, 256, 0, stream>>>(x, emit, T, bufA, scA);
  k_comb8<<<64, 256, 0, stream>>>(bufA, scA, bufB, scB);
  k_comb8<<< 8, 256, 0, stream>>>(bufB, scB, bufC, scC);
  k_comb8<<< 1, 256, 0, stream>>>(bufC, scC, bufD, scD);
  k_final<<<1, 128, 0, stream>>>(bufD, scD, T, out);
}

// Round 4
// 235.681 us; speedup vs baseline: 3.0944x; 2.9882x over previous
//
#include <hip/hip_runtime.h>

#define NTG 128
#define NSTEPS 8191          // SEQ_LEN-1
#define GCH 512              // chunks
#define LCH 16               // steps per chunk
#define MATH16 (NTG*NTG)     // elements per matrix

typedef _Float16 half4v  __attribute__((ext_vector_type(4)));
typedef float    float4v __attribute__((ext_vector_type(4)));

// swizzled index into a [128][128] f16 LDS tile (element units).
// XOR bits 3..6 with row bits 0..3 -> spreads stride-256B rows across banks,
// preserves 4-element (b64) and 2-element (b32) alignment.
__device__ __forceinline__ int su(int row, int col){
  return (row*NTG + col) ^ ((row & 15) << 3);
}

__device__ __forceinline__ float wave_max(float v){
#pragma unroll
  for (int m = 32; m >= 1; m >>= 1) v = fmaxf(v, __shfl_xor(v, m));
  return v;
}
__device__ __forceinline__ float wave_sum(float v){
#pragma unroll
  for (int m = 32; m >= 1; m >>= 1) v += __shfl_xor(v, m);
  return v;
}

// ---------------- kernel 1: per-chunk scaled transfer matrices (MFMA f16) ----------------
// State X = M_s row-major f16 (swizzled) in LDS, max-normalized; log-scale in double.
// Step: D = (E^T)(M_s^T) via mfma_16x16x16_f16; D[j][i]*eh[j], renorm, write X[i][j].
// NOTE: every loop touching accv/aE/bf MUST be fully unrolled — runtime-indexed
// ext_vector arrays go to scratch (rule #20; round-3 showed 1.2 GB spill traffic).
__global__ __launch_bounds__(256, 2)
void k_chunks(const int* __restrict__ x, const float* __restrict__ emit,
              const float* __restrict__ T, _Float16* __restrict__ P,
              double* __restrict__ scale)
{
  __shared__ _Float16 X[MATH16];   // 32 KB
  __shared__ float red_g[4];

  const int t    = threadIdx.x;
  const int lane = t & 63, wv = t >> 6;
  const int l15  = lane & 15, g4 = lane >> 4;   // lane>>4 in 0..3
  const int g    = blockIdx.x;
  const int s0   = g*LCH;
  const int nst  = min(LCH, NSTEPS - s0);       // 16 (last chunk 15)

  // --- preload A-fragments: A = E^T, A[j][k] = exp(T[k][j]); fixed for all steps.
  half4v aE[2][8];
#pragma unroll
  for (int jt=0; jt<2; ++jt){
    const int j = (wv*2 + jt)*16 + l15;
#pragma unroll
    for (int ks=0; ks<8; ++ks){
      half4v a;
#pragma unroll
      for (int jj=0; jj<4; ++jj){
        const int k = ks*16 + g4*4 + jj;
        a[jj] = (_Float16)__expf(T[k*NTG + j]);
      }
      aE[jt][ks] = a;
    }
  }

  // --- leaf: X = G_{s0}: X[i][j] = exp(T[i][j]) * eh0[j]
  double cacc;
  {
    const int tok = x[1+s0];
    const float* er = emit + (size_t)tok*NTG;
    float2 me2 = *(const float2*)(er + lane*2);
    const float m0 = wave_max(fmaxf(me2.x, me2.y));
    const float eh0a = __expf(me2.x - m0);      // cols 2*lane, 2*lane+1
    const float eh0b = __expf(me2.y - m0);
    const int j0 = (t & 63)*2;
    for (int it2=0; it2<32; ++it2){
      const int idx = it2*256 + t;
      const int i = idx >> 6;                   // row; j = j0 (2 cols per thread)
      float2 tv = *(const float2*)(T + (size_t)i*NTG + j0);
      union { unsigned int u; _Float16 h[2]; } pk;
      pk.h[0] = (_Float16)(__expf(tv.x)*eh0a);
      pk.h[1] = (_Float16)(__expf(tv.y)*eh0b);
      *(unsigned int*)&X[su(i, j0)] = pk.u;
    }
    cacc = (double)m0;
  }
  __syncthreads();

  float4v accv[2][8];
  for (int s=1; s<nst; ++s){
    const int tok = x[1+s0+s];
    const float* er = emit + (size_t)tok*NTG;
    float2 me2 = *(const float2*)(er + lane*2);
    const float m = wave_max(fmaxf(me2.x, me2.y));
    float eh[2][4];
#pragma unroll
    for (int jt=0; jt<2; ++jt)
#pragma unroll
      for (int r=0; r<4; ++r)
        eh[jt][r] = __expf(er[(wv*2+jt)*16 + g4*4 + r] - m);

#pragma unroll
    for (int jt=0; jt<2; ++jt)
#pragma unroll
      for (int it=0; it<8; ++it) accv[jt][it] = (float4v){0.f,0.f,0.f,0.f};

#pragma unroll
    for (int it=0; it<8; ++it){
      const int c = it*16 + l15;                // B col = i-index of M
      half4v bf[8];
#pragma unroll
      for (int ks=0; ks<8; ++ks)
        bf[ks] = *(half4v*)&X[su(c, ks*16 + g4*4)];   // B[k][c] = M[c][k]
#pragma unroll
      for (int jt=0; jt<2; ++jt)
#pragma unroll
        for (int ks=0; ks<8; ++ks)
          accv[jt][it] = __builtin_amdgcn_mfma_f32_16x16x16f16(aE[jt][ks], bf[ks], accv[jt][it], 0,0,0);
    }

    float gm = 0.f;
#pragma unroll
    for (int jt=0; jt<2; ++jt)
#pragma unroll
      for (int it=0; it<8; ++it)
#pragma unroll
        for (int r=0;r<4;r++){
          float v = accv[jt][it][r] * eh[jt][r];
          accv[jt][it][r] = v;
          gm = fmaxf(gm, v);
        }
    gm = wave_max(gm);
    if (lane==0) red_g[wv] = gm;
    __syncthreads();                            // barA: all B-frag reads done + red_g ready
    const float gmax = fmaxf(fmaxf(red_g[0],red_g[1]), fmaxf(red_g[2],red_g[3]));
    const float inv  = 1.0f/gmax;
    cacc += (double)m + (double)__logf(gmax);
#pragma unroll
    for (int jt=0; jt<2; ++jt)
#pragma unroll
      for (int it=0; it<8; ++it){
        const int i  = it*16 + l15;
        const int jb = (wv*2+jt)*16 + g4*4;
        half4v h;
#pragma unroll
        for (int r=0;r<4;r++) h[r] = (_Float16)(accv[jt][it][r]*inv);
        *(half4v*)&X[su(i, jb)] = h;            // X[i][jb..jb+3] contiguous
      }
    __syncthreads();                            // barB: X writes visible
  }

  // store row-major f16 P[g] (unswizzle via matching su reads)
  _Float16* Pg = P + (size_t)g*MATH16;
  for (int it2=0; it2<32; ++it2){
    const int idx = it2*256 + t;
    const int i = idx >> 6, j = (t & 63)*2;
    ((unsigned int*)Pg)[idx] = *(unsigned int*)&X[su(i, j)];
  }
  if (t==0) scale[g] = cacc;
}

// ---------------- kernel 2: fan-in-8 combine with per-multiply renorm (MFMA f16) ----------------
__global__ __launch_bounds__(256, 2)
void k_comb8(const _Float16* __restrict__ Pin, const double* __restrict__ Sin,
             _Float16* __restrict__ Pout, double* __restrict__ Sout)
{
  __shared__ _Float16 X[MATH16];
  __shared__ float red_g[4];
  const int t    = threadIdx.x;
  const int lane = t & 63, wv = t >> 6;
  const int l15  = lane & 15, g4 = lane >> 4;
  const int p    = blockIdx.x;
  const _Float16* A0 = Pin + (size_t)p*8*MATH16;

  // stage X = first matrix (row-major -> swizzled)
  for (int it2=0; it2<32; ++it2){
    const int idx = it2*256 + t;
    const int i = idx >> 6, j = (t & 63)*2;
    *(unsigned int*)&X[su(i, j)] = ((const unsigned int*)A0)[idx];
  }
  double slog = 0.0;
  __syncthreads();

  float4v accv[2][8];
  for (int mi=1; mi<8; ++mi){
    const _Float16* B = A0 + (size_t)mi*MATH16;
    // A-fragments = B^T from global: A[j][k] = B[k][j]
    half4v aB[2][8];
#pragma unroll
    for (int jt=0; jt<2; ++jt){
      const int j = (wv*2 + jt)*16 + l15;
#pragma unroll
      for (int ks=0; ks<8; ++ks){
        half4v a;
#pragma unroll
        for (int jj=0; jj<4; ++jj) a[jj] = B[(size_t)(ks*16 + g4*4 + jj)*NTG + j];
        aB[jt][ks] = a;
      }
    }

#pragma unroll
    for (int jt=0; jt<2; ++jt)
#pragma unroll
      for (int it=0; it<8; ++it) accv[jt][it] = (float4v){0.f,0.f,0.f,0.f};

#pragma unroll
    for (int it=0; it<8; ++it){
      const int c = it*16 + l15;
      half4v bf[8];
#pragma unroll
      for (int ks=0; ks<8; ++ks)
        bf[ks] = *(half4v*)&X[su(c, ks*16 + g4*4)];
#pragma unroll
      for (int jt=0; jt<2; ++jt)
#pragma unroll
        for (int ks=0; ks<8; ++ks)
          accv[jt][it] = __builtin_amdgcn_mfma_f32_16x16x16f16(aB[jt][ks], bf[ks], accv[jt][it], 0,0,0);
    }

    float gm = 0.f;
#pragma unroll
    for (int jt=0; jt<2; ++jt)
#pragma unroll
      for (int it=0; it<8; ++it)
#pragma unroll
        for (int r=0;r<4;r++) gm = fmaxf(gm, accv[jt][it][r]);
    gm = wave_max(gm);
    if (lane==0) red_g[wv] = gm;
    __syncthreads();
    const float gmax = fmaxf(fmaxf(red_g[0],red_g[1]), fmaxf(red_g[2],red_g[3]));
    const float inv  = 1.0f/gmax;
    slog += (double)__logf(gmax);
#pragma unroll
    for (int jt=0; jt<2; ++jt)
#pragma unroll
      for (int it=0; it<8; ++it){
        const int i  = it*16 + l15;
        const int jb = (wv*2+jt)*16 + g4*4;
        half4v h;
#pragma unroll
        for (int r=0;r<4;r++) h[r] = (_Float16)(accv[jt][it][r]*inv);
        *(half4v*)&X[su(i, jb)] = h;
      }
    __syncthreads();
  }

  _Float16* Po = Pout + (size_t)p*MATH16;
  for (int it2=0; it2<32; ++it2){
    const int idx = it2*256 + t;
    const int i = idx >> 6, j = (t & 63)*2;
    ((unsigned int*)Po)[idx] = *(unsigned int*)&X[su(i, j)];
  }
  if (t==0){
    double ssum = slog;
    for (int q=0;q<8;q++) ssum += Sin[p*8+q];
    Sout[p] = ssum;
  }
}

// ---------------- kernel 3: finalize z ----------------
__global__ void k_final(const _Float16* __restrict__ Pf, const double* __restrict__ Sf,
                        const float* __restrict__ T, float* __restrict__ out)
{
  __shared__ float rmax[2], rsum[2];
  const int t = threadIdx.x;          // 128 threads
  const int wv = t>>6, lane = t&63;
  float val = logf((float)Pf[t]) + T[t*NTG + 1];   // row START=0 of product; END tag = 1
  float mx = wave_max(val);
  if (lane==0) rmax[wv] = mx;
  __syncthreads();
  mx = fmaxf(rmax[0], rmax[1]);
  float e = expf(val - mx);
  float s = wave_sum(e);
  if (lane==0) rsum[wv] = s;
  __syncthreads();
  if (t==0){
    double z = (double)mx + log((double)(rsum[0]+rsum[1])) + Sf[0];
    out[0] = (float)z;
  }
}

extern "C" void kernel_launch(void* const* d_in, const int* in_sizes, int n_in,
                              void* d_out, int out_size, void* d_ws, size_t ws_size,
                              hipStream_t stream)
{
  const int*   x    = (const int*)d_in[0];
  const float* emit = (const float*)d_in[1];
  const float* T    = (const float*)d_in[2];
  float* out = (float*)d_out;

  // ws: f16 bufA[512 mats] | bufB[64] | bufC[8] | bufD[1] | doubles scA[512] scB[64] scC[8] scD[1]
  _Float16* bufA = (_Float16*)d_ws;
  _Float16* bufB = bufA + (size_t)512*MATH16;
  _Float16* bufC = bufB + (size_t)64*MATH16;
  _Float16* bufD = bufC + (size_t)8*MATH16;
  double* scA = (double*)(bufD + MATH16);
  double* scB = scA + 512;
  double* scC = scB + 64;
  double* scD = scC + 8;

  k_chunks<<<GCH, 256, 0, stream>>>(x, emit, T, bufA, scA);
  k_comb8<<<64, 256, 0, stream>>>(bufA, scA, bufB, scB);
  k_comb8<<< 8, 256, 0, stream>>>(bufB, scB, bufC, scC);
  k_comb8<<< 1, 256, 0, stream>>>(bufC, scC, bufD, scD);
  k_final<<<1, 128, 0, stream>>>(bufD, scD, T, out);
}

// Round 5
// 181.345 us; speedup vs baseline: 4.0215x; 1.2996x over previous
//
#include <hip/hip_runtime.h>

#define NTG 128
#define NSTEPS 8191          // SEQ_LEN-1
#define GCH 512              // chunks
#define LCH 16               // steps per chunk
#define MATF16 (NTG*NTG)

typedef _Float16 half8v  __attribute__((ext_vector_type(8)));
typedef _Float16 half4v  __attribute__((ext_vector_type(4)));
typedef float    float4v __attribute__((ext_vector_type(4)));

// swizzled index into a [128][128] f16 LDS tile (element units).
// XOR bits 3..6 with row bits 0..3; preserves 8-elem (b128) alignment.
__device__ __forceinline__ int su(int row, int col){
  return (row*NTG + col) ^ ((row & 15) << 3);
}

__device__ __forceinline__ float wave_max(float v){
#pragma unroll
  for (int m = 32; m >= 1; m >>= 1) v = fmaxf(v, __shfl_xor(v, m));
  return v;
}
__device__ __forceinline__ float wave_sum(float v){
#pragma unroll
  for (int m = 32; m >= 1; m >>= 1) v += __shfl_xor(v, m);
  return v;
}

// ---------------- kernel 1: per-chunk transfer matrices, K=32 MFMA ----------------
// State M (normal orientation) in LDS f16, UNNORMALIZED (bounded <= 128*e^maxT);
// 1/gmax of prev step folded into ehp (linear).  Writes Pn = M and Pt = M^T.
__global__ __launch_bounds__(256, 2)
void k_chunks(const int* __restrict__ x, const float* __restrict__ emit,
              const float* __restrict__ T, _Float16* __restrict__ Pn,
              _Float16* __restrict__ Pt, double* __restrict__ scale)
{
  __shared__ _Float16 X[MATF16];    // 32 KB
  __shared__ float red_g[2][4];

  const int t = threadIdx.x;
  const int lane = t & 63, wv = t >> 6;
  const int l15 = lane & 15, g4 = lane >> 4;
  const int g = blockIdx.x;
  const int s0 = g*LCH;
  const int nst = min(LCH, NSTEPS - s0);

  // A = E^T fragments (fixed): A[j][k] = exp(T[k][j]); k-slots: ks*32 + g4*8 + jj
  half8v aE[2][4];
#pragma unroll
  for (int jt=0; jt<2; ++jt){
    const int j = (wv*2+jt)*16 + l15;
#pragma unroll
    for (int ks=0; ks<4; ++ks){
      half8v a;
#pragma unroll
      for (int jj=0; jj<8; ++jj)
        a[jj] = (_Float16)__expf(T[(ks*32 + g4*8 + jj)*NTG + j]);
      aE[jt][ks] = a;
    }
  }

  // leaf: X = exp(T) .* exp(emit0 - m0) / 128   (entries <= ~0.6)
  double cacc;
  {
    const int tok = x[1+s0];
    const float* er = emit + (size_t)tok*NTG;
    const float2 me2 = *(const float2*)(er + lane*2);
    const float m0 = wave_max(fmaxf(me2.x, me2.y));
    const float sa = __expf(me2.x - m0) * 0.0078125f;
    const float sb = __expf(me2.y - m0) * 0.0078125f;
    const int j0 = lane*2;
    for (int it2=0; it2<32; ++it2){
      const int idx = it2*256 + t;
      const int i = idx >> 6;
      const float2 tv = *(const float2*)(T + (size_t)i*NTG + j0);
      union { unsigned int u; _Float16 h[2]; } pk;
      pk.h[0] = (_Float16)(__expf(tv.x)*sa);
      pk.h[1] = (_Float16)(__expf(tv.y)*sb);
      *(unsigned int*)&X[su(i, j0)] = pk.u;
    }
    cacc = (double)m0 + 4.852030263919617;   // + log(128)
  }
  __syncthreads();

  float pscale = 1.0f;
  float4v accv[2][8];
  for (int s=1; s<nst; ++s){
    const int tok = x[1+s0+s];
    const float* er = emit + (size_t)tok*NTG;
    const float2 me2 = *(const float2*)(er + lane*2);
    const float m = wave_max(fmaxf(me2.x, me2.y));
    float ehp[2][4];
#pragma unroll
    for (int jt=0; jt<2; ++jt)
#pragma unroll
      for (int r=0; r<4; ++r)
        ehp[jt][r] = __expf(er[(wv*2+jt)*16 + g4*4 + r] - m) * pscale;

#pragma unroll
    for (int jt=0; jt<2; ++jt)
#pragma unroll
      for (int it=0; it<8; ++it) accv[jt][it] = (float4v){0.f,0.f,0.f,0.f};

#pragma unroll
    for (int it=0; it<8; ++it){
      const int c = it*16 + l15;
      half8v bf[4];
#pragma unroll
      for (int ks=0; ks<4; ++ks)
        bf[ks] = *(const half8v*)&X[su(c, ks*32 + g4*8)];   // B[k][c] = M[c][k]
#pragma unroll
      for (int jt=0; jt<2; ++jt)
#pragma unroll
        for (int ks=0; ks<4; ++ks)
          accv[jt][it] = __builtin_amdgcn_mfma_f32_16x16x32_f16(aE[jt][ks], bf[ks], accv[jt][it], 0,0,0);
    }

    float gm = 0.f;
#pragma unroll
    for (int jt=0; jt<2; ++jt)
#pragma unroll
      for (int it=0; it<8; ++it)
#pragma unroll
        for (int r=0;r<4;r++){
          const float v = accv[jt][it][r]*ehp[jt][r];
          accv[jt][it][r] = v;
          gm = fmaxf(gm, v);
        }
    __syncthreads();                          // bar1: all X reads done
#pragma unroll
    for (int jt=0; jt<2; ++jt)
#pragma unroll
      for (int it=0; it<8; ++it){
        half4v h;
#pragma unroll
        for (int r=0;r<4;r++) h[r] = (_Float16)accv[jt][it][r];
        *(half4v*)&X[su(it*16 + l15, (wv*2+jt)*16 + g4*4)] = h;   // raw (unnormalized)
      }
    gm = wave_max(gm);
    if (lane==0) red_g[s&1][wv] = gm;
    __syncthreads();                          // bar2: X writes + red_g visible
    const float gmax = fmaxf(fmaxf(red_g[s&1][0],red_g[s&1][1]),
                             fmaxf(red_g[s&1][2],red_g[s&1][3]));
    pscale = 1.0f/gmax;
    cacc += (double)m + (double)__logf(gmax);
  }

  const float inv = pscale;   // 1/gmax_last -> stored matrices have max == 1
  unsigned int* pn = (unsigned int*)(Pn + (size_t)g*MATF16);
  unsigned int* pt = (unsigned int*)(Pt + (size_t)g*MATF16);
  for (int it2=0; it2<32; ++it2){
    const int idx = it2*256 + t;
    const int i = idx >> 6, j0 = (t&63)*2;
    union { unsigned int u; _Float16 h[2]; } pk;
    pk.u = *(const unsigned int*)&X[su(i, j0)];
    pk.h[0] = (_Float16)((float)pk.h[0]*inv);
    pk.h[1] = (_Float16)((float)pk.h[1]*inv);
    pn[idx] = pk.u;
  }
  for (int it2=0; it2<32; ++it2){
    const int uidx = it2*256 + t;
    const int jj = uidx >> 6, ii = (t&63)*2;
    union { unsigned int u; _Float16 h[2]; } pk;
    pk.h[0] = (_Float16)((float)X[su(ii,   jj)]*inv);
    pk.h[1] = (_Float16)((float)X[su(ii+1, jj)]*inv);
    pt[uidx] = pk.u;
  }
  if (t==0) scale[g] = cacc;
}

// ---------------- kernel 2: fan-in-8 combine: R_k = Yt_k * R_{k-1} ----------------
// X holds R^T; A-fragments are contiguous vector loads from Pt (transposed mats).
__global__ __launch_bounds__(256, 2)
void k_comb8(const _Float16* __restrict__ Pn_in, const _Float16* __restrict__ Pt_in,
             const double* __restrict__ Sin,
             _Float16* __restrict__ Pn_out, _Float16* __restrict__ Pt_out,
             double* __restrict__ Sout)
{
  __shared__ _Float16 X[MATF16];
  __shared__ float red_g[2][4];
  const int t = threadIdx.x;
  const int lane = t & 63, wv = t >> 6;
  const int l15 = lane & 15, g4 = lane >> 4;
  const int p = blockIdx.x;

  // X = R_0^T = M_{8p}  (normal orientation input)
  const unsigned int* src = (const unsigned int*)(Pn_in + (size_t)p*8*MATF16);
  for (int it2=0; it2<32; ++it2){
    const int idx = it2*256 + t;
    const int i = idx >> 6, j0 = (t&63)*2;
    *(unsigned int*)&X[su(i, j0)] = src[idx];
  }
  __syncthreads();

  float pscale = 1.0f;
  double slog = 0.0;
  float4v accv[2][8];
  for (int mi=1; mi<8; ++mi){
    const _Float16* Yt = Pt_in + (size_t)(p*8+mi)*MATF16;
    half8v aB[2][4];
#pragma unroll
    for (int jt=0; jt<2; ++jt){
      const int j = (wv*2+jt)*16 + l15;
#pragma unroll
      for (int ks=0; ks<4; ++ks)
        aB[jt][ks] = *(const half8v*)(Yt + (size_t)j*NTG + ks*32 + g4*8);
    }

#pragma unroll
    for (int jt=0; jt<2; ++jt)
#pragma unroll
      for (int it=0; it<8; ++it) accv[jt][it] = (float4v){0.f,0.f,0.f,0.f};

#pragma unroll
    for (int it=0; it<8; ++it){
      const int c = it*16 + l15;
      half8v bf[4];
#pragma unroll
      for (int ks=0; ks<4; ++ks)
        bf[ks] = *(const half8v*)&X[su(c, ks*32 + g4*8)];
#pragma unroll
      for (int jt=0; jt<2; ++jt)
#pragma unroll
        for (int ks=0; ks<4; ++ks)
          accv[jt][it] = __builtin_amdgcn_mfma_f32_16x16x32_f16(aB[jt][ks], bf[ks], accv[jt][it], 0,0,0);
    }

    float gm = 0.f;
#pragma unroll
    for (int jt=0; jt<2; ++jt)
#pragma unroll
      for (int it=0; it<8; ++it)
#pragma unroll
        for (int r=0;r<4;r++){
          const float v = accv[jt][it][r]*pscale;
          accv[jt][it][r] = v;
          gm = fmaxf(gm, v);
        }
    __syncthreads();                          // bar1
#pragma unroll
    for (int jt=0; jt<2; ++jt)
#pragma unroll
      for (int it=0; it<8; ++it){
        half4v h;
#pragma unroll
        for (int r=0;r<4;r++) h[r] = (_Float16)accv[jt][it][r];
        *(half4v*)&X[su(it*16 + l15, (wv*2+jt)*16 + g4*4)] = h;
      }
    gm = wave_max(gm);
    if (lane==0) red_g[mi&1][wv] = gm;
    __syncthreads();                          // bar2
    const float gmax = fmaxf(fmaxf(red_g[mi&1][0],red_g[mi&1][1]),
                             fmaxf(red_g[mi&1][2],red_g[mi&1][3]));
    pscale = 1.0f/gmax;
    slog += (double)__logf(gmax);
  }

  const float inv = pscale;
  // X = R_7^T = C_p (normal) -> linear dump = Pn_out; transposed read = Pt_out
  unsigned int* pn = (unsigned int*)(Pn_out + (size_t)p*MATF16);
  unsigned int* pt = (unsigned int*)(Pt_out + (size_t)p*MATF16);
  for (int it2=0; it2<32; ++it2){
    const int idx = it2*256 + t;
    const int i = idx >> 6, j0 = (t&63)*2;
    union { unsigned int u; _Float16 h[2]; } pk;
    pk.u = *(const unsigned int*)&X[su(i, j0)];
    pk.h[0] = (_Float16)((float)pk.h[0]*inv);
    pk.h[1] = (_Float16)((float)pk.h[1]*inv);
    pn[idx] = pk.u;
  }
  for (int it2=0; it2<32; ++it2){
    const int uidx = it2*256 + t;
    const int jj = uidx >> 6, ii = (t&63)*2;
    union { unsigned int u; _Float16 h[2]; } pk;
    pk.h[0] = (_Float16)((float)X[su(ii,   jj)]*inv);
    pk.h[1] = (_Float16)((float)X[su(ii+1, jj)]*inv);
    pt[uidx] = pk.u;
  }
  if (t==0){
    double ssum = slog;
#pragma unroll
    for (int q=0;q<8;q++) ssum += Sin[p*8+q];
    Sout[p] = ssum;
  }
}

// ---------------- kernel 3: matvec chain over 8 transposed mats + final lse ----------------
__global__ void k_final(const _Float16* __restrict__ PtC, const double* __restrict__ scC,
                        const float* __restrict__ T, float* __restrict__ out)
{
  __shared__ float u[2][NTG];
  __shared__ float red[4], red2[4];
  const int t = threadIdx.x;            // 256 threads
  const int lane = t & 63, wv = t >> 6;

  double acc = 0.0;
#pragma unroll
  for (int q=0;q<8;q++) acc += scC[q];

  if (t < NTG) u[0][t] = (t==0) ? 1.f : 0.f;    // e_START
  __syncthreads();

  int cur = 0;
  const int r = t >> 1, off = (t&1)*64;
  for (int k=0;k<8;k++){
    const _Float16* Y = PtC + (size_t)k*MATF16 + (size_t)r*NTG + off;
    float dot = 0.f;
#pragma unroll
    for (int q=0;q<8;q++){
      const half8v h = *(const half8v*)(Y + q*8);
#pragma unroll
      for (int e=0;e<8;e++) dot += (float)h[e]*u[cur][off + q*8 + e];
    }
    dot += __shfl_xor(dot, 1);
    if ((t&1)==0) u[cur^1][r] = dot;    // growth <= 128^8 < f32 max: no renorm
    __syncthreads();
    cur ^= 1;
  }

  const float val = (t < NTG) ? (__logf(u[cur][t]) + T[t*NTG + 1]) : -3.0e38f;
  float mx = wave_max(val);
  if (lane==0) red[wv] = mx;
  __syncthreads();
  mx = fmaxf(fmaxf(red[0],red[1]), fmaxf(red[2],red[3]));
  const float e = (t < NTG) ? __expf(val - mx) : 0.f;
  const float s = wave_sum(e);
  if (lane==0) red2[wv] = s;
  __syncthreads();
  if (t==0){
    const double z = (double)mx + log((double)(red2[0]+red2[1]+red2[2]+red2[3])) + acc;
    out[0] = (float)z;
  }
}

extern "C" void kernel_launch(void* const* d_in, const int* in_sizes, int n_in,
                              void* d_out, int out_size, void* d_ws, size_t ws_size,
                              hipStream_t stream)
{
  const int*   x    = (const int*)d_in[0];
  const float* emit = (const float*)d_in[1];
  const float* T    = (const float*)d_in[2];
  float* out = (float*)d_out;

  // ws: f16 PnA[512] PtA[512] PnB[64] PtB[64] PnC[8] PtC[8] | dbl scA[512] scB[64] scC[8]
  _Float16* PnA = (_Float16*)d_ws;
  _Float16* PtA = PnA + (size_t)512*MATF16;
  _Float16* PnB = PtA + (size_t)512*MATF16;
  _Float16* PtB = PnB + (size_t)64*MATF16;
  _Float16* PnC = PtB + (size_t)64*MATF16;
  _Float16* PtC = PnC + (size_t)8*MATF16;
  double* scA = (double*)(PtC + (size_t)8*MATF16);
  double* scB = scA + 512;
  double* scC = scB + 64;

  k_chunks<<<GCH, 256, 0, stream>>>(x, emit, T, PnA, PtA, scA);
  k_comb8<<<64, 256, 0, stream>>>(PnA, PtA, scA, PnB, PtB, scB);
  k_comb8<<< 8, 256, 0, stream>>>(PnB, PtB, scB, PnC, PtC, scC);
  k_final<<<1, 256, 0, stream>>>(PtC, scC, T, out);
}